// Round 4
// baseline (1400.341 us; speedup 1.0000x reference)
//
#include <hip/hip_runtime.h>
#include <hip/hip_bf16.h>
#include <stdint.h>

// QuantizedLinear on MI355X (gfx950).
//   C[8192,11008] = x[8192,4096] . W^T,  W[n,k] = (q - zero)*scale, group=128
// Round 4: 256x256 tile, BK=64, 8 waves, mfma_f32_32x32x16_f16 (8/phase),
// balanced 4-phase/K-tile schedule, 2-buf LDS (128 KiB) with XOR swizzle
// (0 bank conflicts, verified round 3), counted vmcnt(4) once per K-tile.
// Schedule per tile T (buf=T&1): reads 8/8/4/4; stages A(T+1)->nbuf at ph a/b,
// B(T+2)->buf at ph c/d (B-buf free after ph b); vmcnt(4) after MM(kk3) keeps
// only B(T+2) in flight. All staged loads have >=3.5 phases of latency cover.

#define M_DIM 8192
#define K_DIM 4096
#define N_DIM 11008

typedef _Float16 f16x8 __attribute__((ext_vector_type(8)));
typedef float f32x16 __attribute__((ext_vector_type(16)));

// ---------- qweight dtype probe (int8 vs int32 encoding) ----------
__device__ __forceinline__ bool q_is_int8(const void* q) {
  const unsigned* w = (const unsigned*)q;
  unsigned m = 0;
#pragma unroll
  for (int i = 0; i < 16; ++i) m |= w[i] & 0xFFFFFF00u;
  return m != 0u;
}

// ---------- x: fp32 -> f16 ----------
__global__ void cvt_x_kernel(const float* __restrict__ X, _Float16* __restrict__ Xh, long total) {
  long e = ((long)blockIdx.x * blockDim.x + threadIdx.x) * 8;
  const long stride = (long)gridDim.x * blockDim.x * 8;
  for (; e < total; e += stride) {
    const float4 a = *(const float4*)(X + e);
    const float4 b = *(const float4*)(X + e + 4);
    f16x8 o;
    o[0] = (_Float16)a.x; o[1] = (_Float16)a.y; o[2] = (_Float16)a.z; o[3] = (_Float16)a.w;
    o[4] = (_Float16)b.x; o[5] = (_Float16)b.y; o[6] = (_Float16)b.z; o[7] = (_Float16)b.w;
    *(f16x8*)(Xh + e) = o;
  }
}

// ---------- W: groupwise dequant -> f16 [N_DIM][K_DIM] ----------
__global__ void dequant_w_kernel(const void* __restrict__ qraw,
                                 const float* __restrict__ scales,
                                 const float* __restrict__ zeros,
                                 _Float16* __restrict__ W) {
  const bool is8 = q_is_int8(qraw);
  const long total = (long)N_DIM * K_DIM;
  long e = ((long)blockIdx.x * blockDim.x + threadIdx.x) * 8;
  const long stride = (long)gridDim.x * blockDim.x * 8;
  for (; e < total; e += stride) {
    const long g = e >> 7;
    const float s = scales[g];
    const float z = zeros[g];
    float v[8];
    if (is8) {
      const uint2 p = *(const uint2*)((const uint8_t*)qraw + e);
      const unsigned a = p.x, b = p.y;
      v[0] = (float)(a & 0xFF);         v[1] = (float)((a >> 8) & 0xFF);
      v[2] = (float)((a >> 16) & 0xFF); v[3] = (float)(a >> 24);
      v[4] = (float)(b & 0xFF);         v[5] = (float)((b >> 8) & 0xFF);
      v[6] = (float)((b >> 16) & 0xFF); v[7] = (float)(b >> 24);
    } else {
      const int* qi = (const int*)qraw;
      const int4 p0 = *(const int4*)(qi + e);
      const int4 p1 = *(const int4*)(qi + e + 4);
      v[0] = (float)p0.x; v[1] = (float)p0.y; v[2] = (float)p0.z; v[3] = (float)p0.w;
      v[4] = (float)p1.x; v[5] = (float)p1.y; v[6] = (float)p1.z; v[7] = (float)p1.w;
    }
    f16x8 o;
#pragma unroll
    for (int k = 0; k < 8; ++k) o[k] = (_Float16)((v[k] - z) * s);
    *(f16x8*)(W + e) = o;
  }
}

// ---------- 32x32-MFMA 4-phase f16 GEMM ----------
__global__ __launch_bounds__(512, 2) void gemm_f16_3232(
    const _Float16* __restrict__ A, const _Float16* __restrict__ B,
    float* __restrict__ C) {
  // per buf: 256 rows x 64 halfwords (8 slots of 16B) = 32 KiB
  __shared__ __align__(16) _Float16 As[2][16384];
  __shared__ __align__(16) _Float16 Bs[2][16384];

  const int t = threadIdx.x;
  // XCD swizzle: 1376 % 8 == 0 -> bijective; 172 blocks/XCD, bm-major.
  const int sw = ((blockIdx.x & 7) * 172) + (blockIdx.x >> 3);
  const int bm = sw & 31;   // 0..31
  const int bn = sw >> 5;   // 0..42

  const int w = t >> 6, l = t & 63;
  const int wm = w >> 2, wn = w & 3;   // wave grid 2M x 4N; per-wave out 128x64
  const int l31 = l & 31, hi2 = l >> 5;
  const int s7 = l31 & 7;
  // swizzled 16B-slot (in halfwords) for kk=0..3: slot = (2*kk + hi2) ^ (row&7)
  const int sl0 = ((0 + hi2) ^ s7) * 8;
  const int sl1 = ((2 + hi2) ^ s7) * 8;
  const int sl2 = ((4 + hi2) ^ s7) * 8;
  const int sl3 = ((6 + hi2) ^ s7) * 8;
  const int Abase = (wm * 128 + l31) * 64;   // + mi*2048 + slot
  const int Bbase = (wn * 64 + l31) * 64;    // + ni*2048 + slot

  // staging: thread t -> row (t>>3) (+64j), linear slot t&7; source column
  // slot pre-inverse-swizzled so LDS[row][s] holds global slot s^(row&7).
  const int tr = t >> 3;
  const int ss = ((t & 7) ^ (tr & 7)) * 8;
  const _Float16* Ag = A + (size_t)(bm * 256 + tr) * K_DIM + ss;
  const _Float16* Bg = B + (size_t)(bn * 256 + tr) * K_DIM + ss;

  f32x16 acc[4][2] = {};
  f16x8 af0, af1, af2, af3;
  f16x8 bg00, bg10, bg01, bg11, bg02, bg12, bg03, bg13;  // bg<ni><kk>

#define AS1 const __attribute__((address_space(1))) void*
#define AS3 __attribute__((address_space(3))) void*
#define GLL(src, dst) __builtin_amdgcn_global_load_lds((AS1)(src), (AS3)(dst), 16, 0, 0)
#define STAGE_A_LO(b, kt) do { GLL(Ag + (kt), &As[b][t * 8]); \
                               GLL(Ag + 64 * K_DIM + (kt), &As[b][4096 + t * 8]); } while (0)
#define STAGE_A_HI(b, kt) do { GLL(Ag + 128 * K_DIM + (kt), &As[b][8192 + t * 8]); \
                               GLL(Ag + 192 * K_DIM + (kt), &As[b][12288 + t * 8]); } while (0)
#define STAGE_B_LO(b, kt) do { GLL(Bg + (kt), &Bs[b][t * 8]); \
                               GLL(Bg + 64 * K_DIM + (kt), &Bs[b][4096 + t * 8]); } while (0)
#define STAGE_B_HI(b, kt) do { GLL(Bg + 128 * K_DIM + (kt), &Bs[b][8192 + t * 8]); \
                               GLL(Bg + 192 * K_DIM + (kt), &Bs[b][12288 + t * 8]); } while (0)

#define LDA(b, SL) do { \
    af0 = *(const f16x8*)(&As[b][Abase + (SL)]); \
    af1 = *(const f16x8*)(&As[b][Abase + 2048 + (SL)]); \
    af2 = *(const f16x8*)(&As[b][Abase + 4096 + (SL)]); \
    af3 = *(const f16x8*)(&As[b][Abase + 6144 + (SL)]); } while (0)
#define LDB(b, ni, SL) (*(const f16x8*)(&Bs[b][Bbase + (ni) * 2048 + (SL)]))

#define MM(b0, b1) do { \
    __builtin_amdgcn_s_setprio(1); \
    acc[0][0] = __builtin_amdgcn_mfma_f32_32x32x16_f16(af0, b0, acc[0][0], 0, 0, 0); \
    acc[0][1] = __builtin_amdgcn_mfma_f32_32x32x16_f16(af0, b1, acc[0][1], 0, 0, 0); \
    acc[1][0] = __builtin_amdgcn_mfma_f32_32x32x16_f16(af1, b0, acc[1][0], 0, 0, 0); \
    acc[1][1] = __builtin_amdgcn_mfma_f32_32x32x16_f16(af1, b1, acc[1][1], 0, 0, 0); \
    acc[2][0] = __builtin_amdgcn_mfma_f32_32x32x16_f16(af2, b0, acc[2][0], 0, 0, 0); \
    acc[2][1] = __builtin_amdgcn_mfma_f32_32x32x16_f16(af2, b1, acc[2][1], 0, 0, 0); \
    acc[3][0] = __builtin_amdgcn_mfma_f32_32x32x16_f16(af3, b0, acc[3][0], 0, 0, 0); \
    acc[3][1] = __builtin_amdgcn_mfma_f32_32x32x16_f16(af3, b1, acc[3][1], 0, 0, 0); \
    __builtin_amdgcn_s_setprio(0); } while (0)

#define BAR() do { asm volatile("" ::: "memory"); __builtin_amdgcn_s_barrier(); asm volatile("" ::: "memory"); } while (0)
#define WAITV(n) asm volatile("s_waitcnt vmcnt(" #n ")" ::: "memory")

  // ---- prologue: A(0),B(0)->buf0, B(1)->buf1; drain A(0),B(0) ----
  STAGE_A_LO(0, 0); STAGE_A_HI(0, 0);
  STAGE_B_LO(0, 0); STAGE_B_HI(0, 0);
  STAGE_B_LO(1, 64); STAGE_B_HI(1, 64);
  WAITV(4);
  BAR();

  // ---- per-tile: 4 phases; buf=T&1, A(T+1)->nbuf (ph a/b), B(T+2)->buf (ph c/d)
#define TILE(buf, nbuf, ktA, ktB) do { \
    /* ph a: kk0 */ \
    LDA(buf, sl0); \
    bg00 = LDB(buf, 0, sl0); bg10 = LDB(buf, 1, sl0); \
    bg01 = LDB(buf, 0, sl1); bg11 = LDB(buf, 1, sl1); \
    STAGE_A_LO(nbuf, ktA); \
    BAR(); MM(bg00, bg10); BAR(); \
    /* ph b: kk1 */ \
    LDA(buf, sl1); \
    bg02 = LDB(buf, 0, sl2); bg12 = LDB(buf, 1, sl2); \
    bg03 = LDB(buf, 0, sl3); bg13 = LDB(buf, 1, sl3); \
    STAGE_A_HI(nbuf, ktA); \
    BAR(); MM(bg01, bg11); BAR(); \
    /* ph c: kk2 (B-buf free after ph b reads) */ \
    LDA(buf, sl2); \
    STAGE_B_LO(buf, ktB); \
    BAR(); MM(bg02, bg12); BAR(); \
    /* ph d: kk3; single counted wait per tile, after the MFMA cluster */ \
    LDA(buf, sl3); \
    STAGE_B_HI(buf, ktB); \
    BAR(); MM(bg03, bg13); WAITV(4); BAR(); \
  } while (0)

#pragma unroll 1
  for (int T = 0; T < 64; T += 2) {
    const int ktA0 = ((T + 1) & 63) * 64;
    const int ktB0 = ((T + 2) & 63) * 64;
    TILE(0, 1, ktA0, ktB0);
    const int ktA1 = ((T + 2) & 63) * 64;
    const int ktB1 = ((T + 3) & 63) * 64;
    TILE(1, 0, ktA1, ktB1);
  }

  // ---- C write. 32x32 C/D layout: col = lane&31, row = (reg&3)+8*(reg>>2)+4*(lane>>5)
  const int r0 = bm * 256 + wm * 128 + 4 * hi2;
  const int c0 = bn * 256 + wn * 64 + l31;
#pragma unroll
  for (int mi = 0; mi < 4; ++mi)
#pragma unroll
    for (int ni = 0; ni < 2; ++ni) {
      float* Cf = C + (size_t)(r0 + mi * 32) * N_DIM + c0 + ni * 32;
#pragma unroll
      for (int reg = 0; reg < 16; ++reg) {
        const int rr = (reg & 3) + 8 * (reg >> 2);
        Cf[(size_t)rr * N_DIM] = acc[mi][ni][reg];
      }
    }
#undef TILE
#undef STAGE_A_LO
#undef STAGE_A_HI
#undef STAGE_B_LO
#undef STAGE_B_HI
#undef LDA
#undef LDB
#undef MM
#undef BAR
#undef WAITV
#undef GLL
#undef AS1
#undef AS3
}

extern "C" void kernel_launch(void* const* d_in, const int* in_sizes, int n_in,
                              void* d_out, int out_size, void* d_ws, size_t ws_size,
                              hipStream_t stream) {
  const float* x      = (const float*)d_in[0];
  const void*  qw     = d_in[1];
  const float* scales = (const float*)d_in[2];
  const float* zeros  = (const float*)d_in[3];
  float* out = (float*)d_out;

  const size_t xh_bytes = (size_t)M_DIM * K_DIM * sizeof(_Float16); // 64 MiB
  const size_t wh_bytes = (size_t)N_DIM * K_DIM * sizeof(_Float16); // ~86 MiB
  if (ws_size < xh_bytes + wh_bytes) return;

  _Float16* Xh = (_Float16*)d_ws;
  _Float16* Wh = (_Float16*)((char*)d_ws + xh_bytes);

  cvt_x_kernel<<<2048, 256, 0, stream>>>(x, Xh, (long)M_DIM * K_DIM);
  dequant_w_kernel<<<2048, 256, 0, stream>>>(qw, scales, zeros, Wh);

  gemm_f16_3232<<<dim3((M_DIM / 256) * (N_DIM / 256)), 512, 0, stream>>>(Xh, Wh, out);
}

// Round 5
// 1290.821 us; speedup vs baseline: 1.0848x; 1.0848x over previous
//
#include <hip/hip_runtime.h>
#include <hip/hip_bf16.h>
#include <stdint.h>

// QuantizedLinear on MI355X (gfx950).
//   C[8192,11008] = x[8192,4096] . W^T,  W[n,k] = (q - zero)*scale, group=128
// Round 5: r3 (8-phase 256x256 BK=64, 16x16x32 f16, XOR swizzle, 0 conflicts,
// counted vmcnt(4), 800us) + ONE change: A-fragment register double-buffering
// (afA for sl0-phases, afB for sl1-phases) to break the every-phase WAR hazard
// between ds_read (writing af) and the in-flight MFMA queue (reading af).
// Theory: r3's phase time 1396cyc = LDS(700) + MFMA(659) fully serialized by
// that WAR; with >=2-phase register reuse distance they overlap -> ~max(700,659).

#define M_DIM 8192
#define K_DIM 4096
#define N_DIM 11008

typedef _Float16 f16x8 __attribute__((ext_vector_type(8)));
typedef float f32x4 __attribute__((ext_vector_type(4)));

// ---------- qweight dtype probe (int8 vs int32 encoding) ----------
__device__ __forceinline__ bool q_is_int8(const void* q) {
  const unsigned* w = (const unsigned*)q;
  unsigned m = 0;
#pragma unroll
  for (int i = 0; i < 16; ++i) m |= w[i] & 0xFFFFFF00u;
  return m != 0u;
}

// ---------- x: fp32 -> f16 ----------
__global__ void cvt_x_kernel(const float* __restrict__ X, _Float16* __restrict__ Xh, long total) {
  long e = ((long)blockIdx.x * blockDim.x + threadIdx.x) * 8;
  const long stride = (long)gridDim.x * blockDim.x * 8;
  for (; e < total; e += stride) {
    const float4 a = *(const float4*)(X + e);
    const float4 b = *(const float4*)(X + e + 4);
    f16x8 o;
    o[0] = (_Float16)a.x; o[1] = (_Float16)a.y; o[2] = (_Float16)a.z; o[3] = (_Float16)a.w;
    o[4] = (_Float16)b.x; o[5] = (_Float16)b.y; o[6] = (_Float16)b.z; o[7] = (_Float16)b.w;
    *(f16x8*)(Xh + e) = o;
  }
}

// ---------- W: groupwise dequant -> f16 [N_DIM][K_DIM] ----------
__global__ void dequant_w_kernel(const void* __restrict__ qraw,
                                 const float* __restrict__ scales,
                                 const float* __restrict__ zeros,
                                 _Float16* __restrict__ W) {
  const bool is8 = q_is_int8(qraw);
  const long total = (long)N_DIM * K_DIM;
  long e = ((long)blockIdx.x * blockDim.x + threadIdx.x) * 8;
  const long stride = (long)gridDim.x * blockDim.x * 8;
  for (; e < total; e += stride) {
    const long g = e >> 7;
    const float s = scales[g];
    const float z = zeros[g];
    float v[8];
    if (is8) {
      const uint2 p = *(const uint2*)((const uint8_t*)qraw + e);
      const unsigned a = p.x, b = p.y;
      v[0] = (float)(a & 0xFF);         v[1] = (float)((a >> 8) & 0xFF);
      v[2] = (float)((a >> 16) & 0xFF); v[3] = (float)(a >> 24);
      v[4] = (float)(b & 0xFF);         v[5] = (float)((b >> 8) & 0xFF);
      v[6] = (float)((b >> 16) & 0xFF); v[7] = (float)(b >> 24);
    } else {
      const int* qi = (const int*)qraw;
      const int4 p0 = *(const int4*)(qi + e);
      const int4 p1 = *(const int4*)(qi + e + 4);
      v[0] = (float)p0.x; v[1] = (float)p0.y; v[2] = (float)p0.z; v[3] = (float)p0.w;
      v[4] = (float)p1.x; v[5] = (float)p1.y; v[6] = (float)p1.z; v[7] = (float)p1.w;
    }
    f16x8 o;
#pragma unroll
    for (int k = 0; k < 8; ++k) o[k] = (_Float16)((v[k] - z) * s);
    *(f16x8*)(W + e) = o;
  }
}

// ---------- 8-phase f16 GEMM with af register double-buffering ----------
__global__ __launch_bounds__(512, 2) void gemm_f16_8ph(
    const _Float16* __restrict__ A, const _Float16* __restrict__ B,
    float* __restrict__ C) {
  // per buf: [256 rows][8 slots of 8 halfwords] = 32 KiB; 2 bufs A + 2 bufs B = 128 KiB
  __shared__ __align__(16) _Float16 As[2][16384];
  __shared__ __align__(16) _Float16 Bs[2][16384];

  const int t = threadIdx.x;
  // XCD swizzle: 1376 blocks % 8 == 0 -> bijective; 172 per XCD, bm-major.
  const int sw = ((blockIdx.x & 7) * 172) + (blockIdx.x >> 3);
  const int bm = sw & 31;   // 0..31
  const int bn = sw >> 5;   // 0..42

  const int w = t >> 6, l = t & 63;
  const int wm = w >> 2, wn = w & 3;   // wave grid 2 x 4
  const int fr = l & 15;
  const int hi = l >> 4;
  const int sx = fr & 7;               // row&7 for all fragment rows

  // ds_read halfword offsets: row*64 + swizzled_slot*8
  const int sl0 = ((hi) ^ sx) * 8;       // kk=0: unswizzled slot = hi
  const int sl1 = ((4 + hi) ^ sx) * 8;   // kk=1: unswizzled slot = 4+hi
  const int arow = (wm * 128 + fr) * 64;
  const int brow = (wn * 64 + fr) * 64;

  // staging: thread t, inst (h,j): LDS halfword off = h*8192 + j*4096 + t*8
  //   -> row = h*128 + j*64 + (t>>3), linear slot = t&7; row&7 = (t>>3)&7
  //   source slot = (t&7) ^ ((t>>3)&7)  (inverse swizzle on the global side)
  const int tr = t >> 3;
  const int ss = ((t & 7) ^ (tr & 7)) * 8;
  const _Float16* Ag = A + (size_t)(bm * 256 + tr) * K_DIM + ss;
  const _Float16* Bg = B + (size_t)(bn * 256 + tr) * K_DIM + ss;

  f32x4 acc[8][4] = {};
  f16x8 afA[4], afB[4];     // double-buffered A frags: afA = sl0 phases, afB = sl1 phases
  f16x8 bg0[4], bg1[4];     // B frags: bg0 = kk0 (read ph1/5), bg1 = kk1 (read ph2/6)

#define AS1 const __attribute__((address_space(1))) void*
#define AS3 __attribute__((address_space(3))) void*
#define STAGE_A(b, kt) do { \
    __builtin_amdgcn_global_load_lds((AS1)(Ag + (kt)),                 (AS3)(&As[b][t * 8]), 16, 0, 0); \
    __builtin_amdgcn_global_load_lds((AS1)(Ag +  64 * K_DIM + (kt)),   (AS3)(&As[b][4096 + t * 8]), 16, 0, 0); \
    __builtin_amdgcn_global_load_lds((AS1)(Ag + 128 * K_DIM + (kt)),   (AS3)(&As[b][8192 + t * 8]), 16, 0, 0); \
    __builtin_amdgcn_global_load_lds((AS1)(Ag + 192 * K_DIM + (kt)),   (AS3)(&As[b][12288 + t * 8]), 16, 0, 0); \
  } while (0)
#define STAGE_B_LO(b, kt) do { \
    __builtin_amdgcn_global_load_lds((AS1)(Bg + (kt)),                 (AS3)(&Bs[b][t * 8]), 16, 0, 0); \
    __builtin_amdgcn_global_load_lds((AS1)(Bg +  64 * K_DIM + (kt)),   (AS3)(&Bs[b][4096 + t * 8]), 16, 0, 0); \
  } while (0)
#define STAGE_B_HI(b, kt) do { \
    __builtin_amdgcn_global_load_lds((AS1)(Bg + 128 * K_DIM + (kt)),   (AS3)(&Bs[b][8192 + t * 8]), 16, 0, 0); \
    __builtin_amdgcn_global_load_lds((AS1)(Bg + 192 * K_DIM + (kt)),   (AS3)(&Bs[b][12288 + t * 8]), 16, 0, 0); \
  } while (0)

#define LDA(dst, b, q, sl) do { \
    dst[0] = *(const f16x8*)(&As[b][arow + (q) * 4096 + (sl)]); \
    dst[1] = *(const f16x8*)(&As[b][arow + (q) * 4096 + 1024 + (sl)]); \
    dst[2] = *(const f16x8*)(&As[b][arow + (q) * 4096 + 2048 + (sl)]); \
    dst[3] = *(const f16x8*)(&As[b][arow + (q) * 4096 + 3072 + (sl)]); \
  } while (0)
#define LDB(b, dst, sl) do { \
    dst[0] = *(const f16x8*)(&Bs[b][brow + (sl)]); \
    dst[1] = *(const f16x8*)(&Bs[b][brow + 1024 + (sl)]); \
    dst[2] = *(const f16x8*)(&Bs[b][brow + 2048 + (sl)]); \
    dst[3] = *(const f16x8*)(&Bs[b][brow + 3072 + (sl)]); \
  } while (0)

#define MM(q, afv, bgv) do { \
    __builtin_amdgcn_s_setprio(1); \
    _Pragma("unroll") for (int mi = 0; mi < 4; ++mi) \
      _Pragma("unroll") for (int n = 0; n < 4; ++n) \
        acc[(q) * 4 + mi][n] = __builtin_amdgcn_mfma_f32_16x16x32_f16(afv[mi], bgv[n], acc[(q) * 4 + mi][n], 0, 0, 0); \
    __builtin_amdgcn_s_setprio(0); \
  } while (0)

#define BAR() do { asm volatile("" ::: "memory"); __builtin_amdgcn_s_barrier(); asm volatile("" ::: "memory"); } while (0)
#define WAITV(n) asm volatile("s_waitcnt vmcnt(" #n ")" ::: "memory")

  // prologue: A(0),B(0)->buf0 [8 loads], B(1)->buf1 [4 loads]; drain first 8.
  STAGE_A(0, 0);
  STAGE_B_LO(0, 0); STAGE_B_HI(0, 0);
  STAGE_B_LO(1, 64); STAGE_B_HI(1, 64);
  WAITV(4);
  BAR();

#pragma unroll 1
  for (int i = 0; i < 32; ++i) {
    const int ktA1 = i * 128 + 64;             // tile 2i+1 (always <= 4032)
    const int ktN2 = (i * 128 + 128) & 4095;   // tile 2i+2 (wrap harmless, last iter)
    const int ktN3 = (i * 128 + 192) & 4095;   // tile 2i+3
    // ---- K-tile 2i from buf0 ----
    // ph1: kk0, m0-3  (afA)
    LDA(afA, 0, 0, sl0); LDB(0, bg0, sl0);
    STAGE_A(1, ktA1);
    BAR(); MM(0, afA, bg0); BAR();
    // ph2: kk1, m0-3  (afB)
    LDA(afB, 0, 0, sl1); LDB(0, bg1, sl1);
    BAR(); MM(0, afB, bg1); BAR();
    // ph3: kk0, m4-7  (afA; WAR vs ph1 MFMAs, 2-phase distance)
    LDA(afA, 0, 1, sl0);
    STAGE_B_LO(0, ktN2);
    BAR(); MM(1, afA, bg0); BAR();
    // ph4: kk1, m4-7  (afB)
    LDA(afB, 0, 1, sl1);
    STAGE_B_HI(0, ktN2);
    BAR(); MM(1, afB, bg1); WAITV(4); BAR();
    // ---- K-tile 2i+1 from buf1 ----
    // ph5
    LDA(afA, 1, 0, sl0); LDB(1, bg0, sl0);
    STAGE_A(0, ktN2);
    BAR(); MM(0, afA, bg0); BAR();
    // ph6
    LDA(afB, 1, 0, sl1); LDB(1, bg1, sl1);
    BAR(); MM(0, afB, bg1); BAR();
    // ph7
    LDA(afA, 1, 1, sl0);
    STAGE_B_LO(1, ktN3);
    BAR(); MM(1, afA, bg0); BAR();
    // ph8
    LDA(afB, 1, 1, sl1);
    STAGE_B_HI(1, ktN3);
    BAR(); MM(1, afB, bg1); WAITV(4); BAR();
  }

  // C write: frag (m,n): row = bm*256 + wm*128 + m*16 + hi*4 + r, col = bn*256 + wn*64 + n*16 + fr
  float* Cb = C + (size_t)(bm * 256 + wm * 128 + hi * 4) * N_DIM + bn * 256 + wn * 64 + fr;
#pragma unroll
  for (int m = 0; m < 8; ++m)
#pragma unroll
    for (int r = 0; r < 4; ++r) {
      float* Cr = Cb + (size_t)(m * 16 + r) * N_DIM;
#pragma unroll
      for (int n = 0; n < 4; ++n) Cr[n * 16] = acc[m][n][r];
    }
#undef STAGE_A
#undef STAGE_B_LO
#undef STAGE_B_HI
#undef LDA
#undef LDB
#undef MM
#undef BAR
#undef WAITV
#undef AS1
#undef AS3
}

extern "C" void kernel_launch(void* const* d_in, const int* in_sizes, int n_in,
                              void* d_out, int out_size, void* d_ws, size_t ws_size,
                              hipStream_t stream) {
  const float* x      = (const float*)d_in[0];
  const void*  qw     = d_in[1];
  const float* scales = (const float*)d_in[2];
  const float* zeros  = (const float*)d_in[3];
  float* out = (float*)d_out;

  const size_t xh_bytes = (size_t)M_DIM * K_DIM * sizeof(_Float16); // 64 MiB
  const size_t wh_bytes = (size_t)N_DIM * K_DIM * sizeof(_Float16); // ~86 MiB
  if (ws_size < xh_bytes + wh_bytes) return;

  _Float16* Xh = (_Float16*)d_ws;
  _Float16* Wh = (_Float16*)((char*)d_ws + xh_bytes);

  cvt_x_kernel<<<2048, 256, 0, stream>>>(x, Xh, (long)M_DIM * K_DIM);
  dequant_w_kernel<<<2048, 256, 0, stream>>>(qw, scales, zeros, Wh);

  gemm_f16_8ph<<<dim3((M_DIM / 256) * (N_DIM / 256)), 512, 0, stream>>>(Xh, Wh, out);
}